// Round 2
// baseline (1087.672 us; speedup 1.0000x reference)
//
#include <hip/hip_runtime.h>
#include <hip/hip_fp16.h>

#define MEM  1024
#define B_   128
#define L_   512
#define IN_  512
#define M_   (B_*L_)      // 65536 rows
#define N_   (2*MEM)      // 2048 cols
#define K_   IN_          // 512

#define SCALE_U 16.0f
#define SCALE_W 1024.0f
#define INV_SCALE (1.0f / (16.0f * 1024.0f))

typedef __attribute__((ext_vector_type(8))) _Float16 half8;
typedef __attribute__((ext_vector_type(4))) float f32x4;

__device__ __forceinline__ float fast_tanh(float x) {
    float e = __expf(2.0f * x);
    return 1.0f - 2.0f / (e + 1.0f);
}
__device__ __forceinline__ float fast_sigmoid(float x) {
    return 1.0f / (1.0f + __expf(-x));
}
__device__ __forceinline__ void gl_lds16(const void* g, void* l) {
    __builtin_amdgcn_global_load_lds(
        (const __attribute__((address_space(1))) void*)g,
        (__attribute__((address_space(3))) void*)l, 16, 0, 0);
}

// fp32 -> scaled (hi fp16 RNE, lo fp16 = RNE(x*s - hi)); unbiased 2-way split.
__global__ void split_fp32_fp16x2(const float* __restrict__ in,
                                  unsigned short* __restrict__ hi,
                                  unsigned short* __restrict__ lo,
                                  int n4, float scale) {
    int i = blockIdx.x * 256 + threadIdx.x;
    if (i >= n4) return;
    const float4 v = reinterpret_cast<const float4*>(in)[i];
    float vs[4] = {v.x, v.y, v.z, v.w};
    unsigned short hs_[4], ls_[4];
#pragma unroll
    for (int c = 0; c < 4; ++c) {
        float xs = vs[c] * scale;
        __half h = __float2half_rn(xs);
        float r = xs - __half2float(h);      // exact (split residual representable)
        __half l = __float2half_rn(r);
        hs_[c] = __half_as_ushort(h);
        ls_[c] = __half_as_ushort(l);
    }
    ushort4 h4, l4;
    h4.x = hs_[0]; h4.y = hs_[1]; h4.z = hs_[2]; h4.w = hs_[3];
    l4.x = ls_[0]; l4.y = ls_[1]; l4.z = ls_[2]; l4.w = ls_[3];
    reinterpret_cast<ushort4*>(hi)[i] = h4;
    reinterpret_cast<ushort4*>(lo)[i] = l4;
}

// C[m][n] = (uh+ul)[m]·(wh+wl)[n] / (SU*SW)  via  uh*wh + uh*wl + ul*wh  (f16 MFMA)
// 128x128 tile, BK=32, 4 waves (2x2 of 64x64), 16x16x32 f16 MFMA.
// cols < 1024 -> sb = 5*tanh((c+bias)/5) into ws; cols >= 1024 -> io into d_out h_t.
#define TM 128
#define TN 128
#define BK 32
__global__ __launch_bounds__(256) void gemm_split_kernel(
    const unsigned short* __restrict__ uh, const unsigned short* __restrict__ ul,
    const unsigned short* __restrict__ wh, const unsigned short* __restrict__ wl,
    const float* __restrict__ bias,
    float* __restrict__ sb_out,    // M_ x MEM
    float* __restrict__ io_out) {  // M_ x MEM  (= h_t region of d_out)
    __shared__ __attribute__((aligned(16))) unsigned short Ah[TM * BK];
    __shared__ __attribute__((aligned(16))) unsigned short Al[TM * BK];
    __shared__ __attribute__((aligned(16))) unsigned short Bh[TN * BK];
    __shared__ __attribute__((aligned(16))) unsigned short Bl[TN * BK];

    const int tid  = threadIdx.x;
    const int tileM = blockIdx.x * TM;   // x = M tile -> consecutive blocks share W tile
    const int tileN = blockIdx.y * TN;
    const int lane = tid & 63, w = tid >> 6;
    const int wm = w & 1, wn = w >> 1;
    const int lrow = lane & 15, quad = lane >> 4;

    f32x4 acc[4][4] = {};

    const int idx0 = tid, idx1 = tid + 256;
    const int r0 = idx0 >> 2, g0 = idx0 & 3;
    const int r1 = idx1 >> 2, g1 = idx1 & 3;
    const size_t a0 = (size_t)(tileM + r0) * K_ + g0 * 8;
    const size_t a1 = (size_t)(tileM + r1) * K_ + g1 * 8;
    const size_t b0 = (size_t)(tileN + r0) * K_ + g0 * 8;
    const size_t b1 = (size_t)(tileN + r1) * K_ + g1 * 8;

    for (int kt = 0; kt < K_ / BK; ++kt) {
        const size_t ko = (size_t)kt * BK;
        __syncthreads();
        gl_lds16(uh + a0 + ko, &Ah[idx0 * 8]);
        gl_lds16(uh + a1 + ko, &Ah[idx1 * 8]);
        gl_lds16(ul + a0 + ko, &Al[idx0 * 8]);
        gl_lds16(ul + a1 + ko, &Al[idx1 * 8]);
        gl_lds16(wh + b0 + ko, &Bh[idx0 * 8]);
        gl_lds16(wh + b1 + ko, &Bh[idx1 * 8]);
        gl_lds16(wl + b0 + ko, &Bl[idx0 * 8]);
        gl_lds16(wl + b1 + ko, &Bl[idx1 * 8]);
        __syncthreads();

        half8 ahf[4], alf[4], bhf[4], blf[4];
#pragma unroll
        for (int i = 0; i < 4; ++i) {
            const int ar = wm * 64 + i * 16 + lrow;
            ahf[i] = *(const half8*)&Ah[ar * BK + quad * 8];
            alf[i] = *(const half8*)&Al[ar * BK + quad * 8];
            const int br = wn * 64 + i * 16 + lrow;
            bhf[i] = *(const half8*)&Bh[br * BK + quad * 8];
            blf[i] = *(const half8*)&Bl[br * BK + quad * 8];
        }
#pragma unroll
        for (int i = 0; i < 4; ++i)
#pragma unroll
            for (int j = 0; j < 4; ++j) {
                f32x4 c = acc[i][j];
                c = __builtin_amdgcn_mfma_f32_16x16x32_f16(ahf[i], bhf[j], c, 0, 0, 0);
                c = __builtin_amdgcn_mfma_f32_16x16x32_f16(ahf[i], blf[j], c, 0, 0, 0);
                c = __builtin_amdgcn_mfma_f32_16x16x32_f16(alf[i], bhf[j], c, 0, 0, 0);
                acc[i][j] = c;
            }
    }

    // Epilogue. C/D layout: col = lane&15, row = quad*4 + reg (verified m89/m91).
#pragma unroll
    for (int j = 0; j < 4; ++j) {
        const int col = tileN + wn * 64 + j * 16 + lrow;
        const float bv = bias[col];
        const bool is_sb = col < MEM;            // wave-uniform (16-col groups)
        const int ocol = is_sb ? col : col - MEM;
        float* const optr = is_sb ? sb_out : io_out;
#pragma unroll
        for (int i = 0; i < 4; ++i) {
            const int rowb = tileM + wm * 64 + i * 16 + quad * 4;
#pragma unroll
            for (int r = 0; r < 4; ++r) {
                float v = acc[i][j][r] * INV_SCALE + bv;
                if (is_sb) v = fast_tanh(v * 0.2f) * 5.0f;
                optr[(size_t)(rowb + r) * MEM + ocol] = v;
            }
        }
    }
}

// One thread per (b, m) chain; 512 sequential steps; 4-deep register prefetch.
__global__ __launch_bounds__(256) void scan_kernel(
    const float* __restrict__ sb_ws,
    float* __restrict__ h_t,          // in: io, out: hf sequence (in place)
    const float* __restrict__ h0,
    float* __restrict__ hf_last) {
    const int idx = blockIdx.x * 256 + threadIdx.x;   // 0 .. 131071
    const int b = idx >> 10, m = idx & (MEM - 1);
    float hf = h0[idx];
    float hs = h0[B_ * MEM + idx];
    const size_t base = (size_t)b * L_ * MEM + m;

    float io[4], sbv[4];
#pragma unroll
    for (int j = 0; j < 4; ++j) {
        io[j]  = h_t[base + (size_t)j * MEM];
        sbv[j] = sb_ws[base + (size_t)j * MEM];
    }
    for (int l0 = 0; l0 < L_; l0 += 4) {
        float io_n[4], sb_n[4];
        const bool more = (l0 + 4) < L_;
        if (more) {
#pragma unroll
            for (int j = 0; j < 4; ++j) {
                io_n[j]  = h_t[base + (size_t)(l0 + 4 + j) * MEM];
                sb_n[j]  = sb_ws[base + (size_t)(l0 + 4 + j) * MEM];
            }
        }
#pragma unroll
        for (int j = 0; j < 4; ++j) {
            const float hsb = hs + 0.4f;
            const float x = io[j] + 4.0f * hf - 7.0f * hsb * hsb + sbv[j];
            const float hfn = fast_tanh(x);
            const float eps = 0.9f + 0.9f * fast_sigmoid(10.0f * (hf - 0.5f));
            hs = hs + eps * (hf - hs);
            h_t[base + (size_t)(l0 + j) * MEM] = hfn;
            hf = hfn;
        }
        if (more) {
#pragma unroll
            for (int j = 0; j < 4; ++j) { io[j] = io_n[j]; sbv[j] = sb_n[j]; }
        }
    }
    hf_last[idx] = hf;
}

extern "C" void kernel_launch(void* const* d_in, const int* in_sizes, int n_in,
                              void* d_out, int out_size, void* d_ws, size_t ws_size,
                              hipStream_t stream) {
    const float* u    = (const float*)d_in[0];   // (128,512,512)
    const float* h0   = (const float*)d_in[1];   // (2,128,1024)
    const float* W_im = (const float*)d_in[2];   // (2048,512)
    const float* b_im = (const float*)d_in[3];   // (2048,)

    float* out = (float*)d_out;
    float* h_t = out;                       // 128*512*1024 floats
    float* hf_last = out + (size_t)M_ * MEM;

    // ws layout (~407 MB):
    //   sb  : M_*MEM fp32      = 268,435,456 B
    //   uh  : M_*K_  fp16      =  67,108,864 B
    //   ul  : M_*K_  fp16      =  67,108,864 B
    //   wh  : N_*K_  fp16      =   2,097,152 B
    //   wl  : N_*K_  fp16      =   2,097,152 B
    char* ws = (char*)d_ws;
    float* sb          = (float*)ws;
    unsigned short* uh = (unsigned short*)(ws + 268435456ull);
    unsigned short* ul = (unsigned short*)(ws + 335544320ull);
    unsigned short* wh = (unsigned short*)(ws + 402653184ull);
    unsigned short* wl = (unsigned short*)(ws + 404750336ull);

    // 1) split fp32 -> fp16 hi/lo (scaled to avoid denormal residuals)
    {
        const int n4_u = (M_ * K_) / 4;      // 8,388,608
        const int n4_w = (N_ * K_) / 4;      //   262,144
        split_fp32_fp16x2<<<(n4_u + 255) / 256, 256, 0, stream>>>(u, uh, ul, n4_u, SCALE_U);
        split_fp32_fp16x2<<<(n4_w + 255) / 256, 256, 0, stream>>>(W_im, wh, wl, n4_w, SCALE_W);
    }
    // 2) GEMM + bias + sb/io epilogue
    {
        dim3 grid(M_ / TM, N_ / TN);   // (512, 16)
        gemm_split_kernel<<<grid, 256, 0, stream>>>(uh, ul, wh, wl, b_im, sb, h_t);
    }
    // 3) recurrence scan (in-place over h_t) + hf_last
    {
        scan_kernel<<<(B_ * MEM) / 256, 256, 0, stream>>>(sb, h_t, h0, hf_last);
    }
}

// Round 3
// 863.842 us; speedup vs baseline: 1.2591x; 1.2591x over previous
//
#include <hip/hip_runtime.h>
#include <hip/hip_fp16.h>

#define MEM  1024
#define B_   128
#define L_   512
#define M_   (B_*L_)      // 65536 rows
#define N_   (2*MEM)      // 2048 cols
#define K_   512

#define SCALE_U 16.0f
#define SCALE_W 1024.0f
#define INV_SCALE (1.0f / (16.0f * 1024.0f))

typedef __attribute__((ext_vector_type(8))) _Float16 half8;
typedef __attribute__((ext_vector_type(4))) float f32x4;

__device__ __forceinline__ float fast_tanh(float x) {
    float e = __expf(2.0f * x);
    return 1.0f - 2.0f / (e + 1.0f);
}
__device__ __forceinline__ float fast_sigmoid(float x) {
    return 1.0f / (1.0f + __expf(-x));
}
__device__ __forceinline__ void gl_lds16(const void* g, void* l) {
    __builtin_amdgcn_global_load_lds(
        (const __attribute__((address_space(1))) void*)g,
        (__attribute__((address_space(3))) void*)l, 16, 0, 0);
}

// fp32 -> scaled (hi fp16 RNE, lo fp16 = RNE(x*s - hi)); unbiased 2-way split.
__global__ void split_fp32_fp16x2(const float* __restrict__ in,
                                  unsigned short* __restrict__ hi,
                                  unsigned short* __restrict__ lo,
                                  int n4, float scale) {
    int i = blockIdx.x * 256 + threadIdx.x;
    if (i >= n4) return;
    const float4 v = reinterpret_cast<const float4*>(in)[i];
    float vs[4] = {v.x, v.y, v.z, v.w};
    unsigned short hs_[4], ls_[4];
#pragma unroll
    for (int c = 0; c < 4; ++c) {
        float xs = vs[c] * scale;
        __half h = __float2half_rn(xs);
        float r = xs - __half2float(h);
        __half l = __float2half_rn(r);
        hs_[c] = __half_as_ushort(h);
        ls_[c] = __half_as_ushort(l);
    }
    ushort4 h4, l4;
    h4.x = hs_[0]; h4.y = hs_[1]; h4.z = hs_[2]; h4.w = hs_[3];
    l4.x = ls_[0]; l4.y = ls_[1]; l4.z = ls_[2]; l4.w = ls_[3];
    reinterpret_cast<ushort4*>(hi)[i] = h4;
    reinterpret_cast<ushort4*>(lo)[i] = l4;
}

// Paired-half GEMM: each block computes a 128x128 tile of BOTH column halves
// (c1 = cols [tileN,tileN+128), c2 = cols +1024) and writes the fused
// z = 5*tanh((c1+b1)/5) + (c2+b2).  3-product fp16-split per half.
// XOR-swizzled LDS (kchunk ^ (row>>1)&3) -> conflict-free ds_read_b128.
// Supertile order: 64-block groups = 8 M-tiles x 8 N-pairs for L2/L3 A reuse.
#define TM 128
#define TN 128
#define BK 32
__global__ __launch_bounds__(256, 2) void gemm_paired_kernel(
    const unsigned short* __restrict__ uh, const unsigned short* __restrict__ ul,
    const unsigned short* __restrict__ wh, const unsigned short* __restrict__ wl,
    const float* __restrict__ bias,
    float* __restrict__ z_out) {   // M_ x MEM
    __shared__ __attribute__((aligned(16))) unsigned short Ah[TM * BK];
    __shared__ __attribute__((aligned(16))) unsigned short Al[TM * BK];
    __shared__ __attribute__((aligned(16))) unsigned short Bh0[TN * BK];
    __shared__ __attribute__((aligned(16))) unsigned short Bl0[TN * BK];
    __shared__ __attribute__((aligned(16))) unsigned short Bh1[TN * BK];
    __shared__ __attribute__((aligned(16))) unsigned short Bl1[TN * BK];

    const int tid = threadIdx.x;
    // supertile: group of 64 blocks = 8 M-tiles (fast) x 8 N-pairs
    const int id  = blockIdx.x;                  // 0..4095
    const int mt  = (id >> 6) * 8 + (id & 7);    // 0..511
    const int nt  = (id >> 3) & 7;               // 0..7
    const int tileM = mt * TM;
    const int tileN = nt * TN;

    const int lane = tid & 63, w = tid >> 6;
    const int wm = w & 1, wn = w >> 1;
    const int lrow = lane & 15, quad = lane >> 4;
    const int q2 = quad ^ ((lrow >> 1) & 3);     // bank-conflict XOR swizzle

    f32x4 acc0[4][4] = {};
    f32x4 acc1[4][4] = {};

    // staging chunk assignments (2 chunks per tile per thread)
    const int i0 = tid, i1 = tid + 256;
    const int r0 = i0 >> 2, gs0 = (i0 & 3) ^ ((r0 >> 1) & 3);
    const int r1 = i1 >> 2, gs1 = (i1 & 3) ^ ((r1 >> 1) & 3);
    const size_t sA0 = (size_t)(tileM + r0) * K_ + gs0 * 8;
    const size_t sA1 = (size_t)(tileM + r1) * K_ + gs1 * 8;
    const size_t sB0a = (size_t)(tileN + r0) * K_ + gs0 * 8;
    const size_t sB0b = (size_t)(tileN + r1) * K_ + gs1 * 8;
    const size_t sB1a = (size_t)(tileN + 1024 + r0) * K_ + gs0 * 8;
    const size_t sB1b = (size_t)(tileN + 1024 + r1) * K_ + gs1 * 8;

    for (int kt = 0; kt < K_ / BK; ++kt) {
        const size_t ko = (size_t)kt * BK;
        __syncthreads();
        gl_lds16(uh + sA0 + ko, &Ah[i0 * 8]);
        gl_lds16(uh + sA1 + ko, &Ah[i1 * 8]);
        gl_lds16(ul + sA0 + ko, &Al[i0 * 8]);
        gl_lds16(ul + sA1 + ko, &Al[i1 * 8]);
        gl_lds16(wh + sB0a + ko, &Bh0[i0 * 8]);
        gl_lds16(wh + sB0b + ko, &Bh0[i1 * 8]);
        gl_lds16(wl + sB0a + ko, &Bl0[i0 * 8]);
        gl_lds16(wl + sB0b + ko, &Bl0[i1 * 8]);
        gl_lds16(wh + sB1a + ko, &Bh1[i0 * 8]);
        gl_lds16(wh + sB1b + ko, &Bh1[i1 * 8]);
        gl_lds16(wl + sB1a + ko, &Bl1[i0 * 8]);
        gl_lds16(wl + sB1b + ko, &Bl1[i1 * 8]);
        __syncthreads();

        half8 ahf[4], alf[4];
#pragma unroll
        for (int i = 0; i < 4; ++i) {
            const int ao = ((wm * 64 + i * 16 + lrow) * 4 + q2) * 8;
            ahf[i] = *(const half8*)&Ah[ao];
            alf[i] = *(const half8*)&Al[ao];
        }
#pragma unroll
        for (int j = 0; j < 4; ++j) {
            const int bo = ((wn * 64 + j * 16 + lrow) * 4 + q2) * 8;
            const half8 b0h = *(const half8*)&Bh0[bo];
            const half8 b0l = *(const half8*)&Bl0[bo];
            const half8 b1h = *(const half8*)&Bh1[bo];
            const half8 b1l = *(const half8*)&Bl1[bo];
#pragma unroll
            for (int i = 0; i < 4; ++i) {
                f32x4 c0 = acc0[i][j];
                c0 = __builtin_amdgcn_mfma_f32_16x16x32_f16(ahf[i], b0h, c0, 0, 0, 0);
                c0 = __builtin_amdgcn_mfma_f32_16x16x32_f16(ahf[i], b0l, c0, 0, 0, 0);
                c0 = __builtin_amdgcn_mfma_f32_16x16x32_f16(alf[i], b0h, c0, 0, 0, 0);
                acc0[i][j] = c0;
                f32x4 c1 = acc1[i][j];
                c1 = __builtin_amdgcn_mfma_f32_16x16x32_f16(ahf[i], b1h, c1, 0, 0, 0);
                c1 = __builtin_amdgcn_mfma_f32_16x16x32_f16(ahf[i], b1l, c1, 0, 0, 0);
                c1 = __builtin_amdgcn_mfma_f32_16x16x32_f16(alf[i], b1h, c1, 0, 0, 0);
                acc1[i][j] = c1;
            }
        }
    }

    // Epilogue: fused z = 5*tanh((c1+b1)/5) + (c2+b2).
    // C/D layout: col = lane&15, row = quad*4 + reg.
#pragma unroll
    for (int j = 0; j < 4; ++j) {
        const int c = tileN + wn * 64 + j * 16 + lrow;
        const float b1v = bias[c];
        const float b2v = bias[c + 1024];
#pragma unroll
        for (int i = 0; i < 4; ++i) {
            const int rowb = tileM + wm * 64 + i * 16 + quad * 4;
#pragma unroll
            for (int r = 0; r < 4; ++r) {
                float v1 = acc0[i][j][r] * INV_SCALE + b1v;
                v1 = fast_tanh(v1 * 0.2f) * 5.0f;
                const float v2 = acc1[i][j][r] * INV_SCALE + b2v;
                z_out[(size_t)(rowb + r) * MEM + c] = v1 + v2;
            }
        }
    }
}

// One thread per (b, m) chain; 512 sequential steps; 4-deep register prefetch.
__global__ __launch_bounds__(256) void scan_kernel(
    const float* __restrict__ z,      // M_ x MEM fused io+sb
    float* __restrict__ h_t,          // out: hf sequence
    const float* __restrict__ h0,
    float* __restrict__ hf_last) {
    const int idx = blockIdx.x * 256 + threadIdx.x;   // 0 .. 131071
    const int b = idx >> 10, m = idx & (MEM - 1);
    float hf = h0[idx];
    float hs = h0[B_ * MEM + idx];
    const size_t base = (size_t)b * L_ * MEM + m;

    float zv[4];
#pragma unroll
    for (int j = 0; j < 4; ++j) zv[j] = z[base + (size_t)j * MEM];

    for (int l0 = 0; l0 < L_; l0 += 4) {
        float zn[4];
        const bool more = (l0 + 4) < L_;
        if (more) {
#pragma unroll
            for (int j = 0; j < 4; ++j)
                zn[j] = z[base + (size_t)(l0 + 4 + j) * MEM];
        }
#pragma unroll
        for (int j = 0; j < 4; ++j) {
            const float hsb = hs + 0.4f;
            const float x = zv[j] + 4.0f * hf - 7.0f * hsb * hsb;
            const float hfn = fast_tanh(x);
            const float eps = 0.9f + 0.9f * fast_sigmoid(10.0f * (hf - 0.5f));
            hs = hs + eps * (hf - hs);
            h_t[base + (size_t)(l0 + j) * MEM] = hfn;
            hf = hfn;
        }
        if (more) {
#pragma unroll
            for (int j = 0; j < 4; ++j) zv[j] = zn[j];
        }
    }
    hf_last[idx] = hf;
}

extern "C" void kernel_launch(void* const* d_in, const int* in_sizes, int n_in,
                              void* d_out, int out_size, void* d_ws, size_t ws_size,
                              hipStream_t stream) {
    const float* u    = (const float*)d_in[0];   // (128,512,512)
    const float* h0   = (const float*)d_in[1];   // (2,128,1024)
    const float* W_im = (const float*)d_in[2];   // (2048,512)
    const float* b_im = (const float*)d_in[3];   // (2048,)

    float* out = (float*)d_out;
    float* h_t = out;
    float* hf_last = out + (size_t)M_ * MEM;

    // ws layout (~407 MB):
    //   z   : M_*MEM fp32      = 268,435,456 B
    //   uh  : M_*K_  fp16      =  67,108,864 B
    //   ul  : M_*K_  fp16      =  67,108,864 B
    //   wh  : N_*K_  fp16      =   2,097,152 B
    //   wl  : N_*K_  fp16      =   2,097,152 B
    char* ws = (char*)d_ws;
    float* z           = (float*)ws;
    unsigned short* uh = (unsigned short*)(ws + 268435456ull);
    unsigned short* ul = (unsigned short*)(ws + 335544320ull);
    unsigned short* wh = (unsigned short*)(ws + 402653184ull);
    unsigned short* wl = (unsigned short*)(ws + 404750336ull);

    // 1) split fp32 -> fp16 hi/lo (scaled to avoid denormal residuals)
    {
        const int n4_u = (M_ * K_) / 4;
        const int n4_w = (N_ * K_) / 4;
        split_fp32_fp16x2<<<(n4_u + 255) / 256, 256, 0, stream>>>(u, uh, ul, n4_u, SCALE_U);
        split_fp32_fp16x2<<<(n4_w + 255) / 256, 256, 0, stream>>>(W_im, wh, wl, n4_w, SCALE_W);
    }
    // 2) paired GEMM -> fused z
    {
        gemm_paired_kernel<<<4096, 256, 0, stream>>>(uh, ul, wh, wl, b_im, z);
    }
    // 3) recurrence scan + hf_last
    {
        scan_kernel<<<(B_ * MEM) / 256, 256, 0, stream>>>(z, h_t, h0, hf_last);
    }
}

// Round 4
// 781.521 us; speedup vs baseline: 1.3917x; 1.1053x over previous
//
#include <hip/hip_runtime.h>
#include <hip/hip_fp16.h>

#define MEM  1024
#define B_   128
#define L_   512
#define M_   (B_*L_)      // 65536 rows
#define N_   (2*MEM)      // 2048 cols
#define K_   512

#define SCALE_U 16.0f
#define SCALE_W 1024.0f
#define INV_SCALE (1.0f / (16.0f * 1024.0f))

typedef __attribute__((ext_vector_type(8))) _Float16 half8;
typedef __attribute__((ext_vector_type(4))) float f32x4;

__device__ __forceinline__ float fast_tanh(float x) {
    float e = __expf(2.0f * x);
    return 1.0f - 2.0f / (e + 1.0f);
}
__device__ __forceinline__ float fast_sigmoid(float x) {
    return 1.0f / (1.0f + __expf(-x));
}
__device__ __forceinline__ void gl_lds16(const void* g, void* l) {
    __builtin_amdgcn_global_load_lds(
        (const __attribute__((address_space(1))) void*)g,
        (__attribute__((address_space(3))) void*)l, 16, 0, 0);
}

// fp32 -> scaled (hi fp16 RNE, lo fp16 = RNE(x*s - hi)); unbiased 2-way split.
// Only used for W (4 MB); u is split on the fly inside the GEMM.
__global__ void split_fp32_fp16x2(const float* __restrict__ in,
                                  unsigned short* __restrict__ hi,
                                  unsigned short* __restrict__ lo,
                                  int n4, float scale) {
    int i = blockIdx.x * 256 + threadIdx.x;
    if (i >= n4) return;
    const float4 v = reinterpret_cast<const float4*>(in)[i];
    float vs[4] = {v.x, v.y, v.z, v.w};
    unsigned short hs_[4], ls_[4];
#pragma unroll
    for (int c = 0; c < 4; ++c) {
        float xs = vs[c] * scale;
        __half h = __float2half_rn(xs);
        float r = xs - __half2float(h);
        __half l = __float2half_rn(r);
        hs_[c] = __half_as_ushort(h);
        ls_[c] = __half_as_ushort(l);
    }
    ushort4 h4, l4;
    h4.x = hs_[0]; h4.y = hs_[1]; h4.z = hs_[2]; h4.w = hs_[3];
    l4.x = ls_[0]; l4.y = ls_[1]; l4.z = ls_[2]; l4.w = ls_[3];
    reinterpret_cast<ushort4*>(hi)[i] = h4;
    reinterpret_cast<ushort4*>(lo)[i] = l4;
}

// Paired-half GEMM, fp32-A staged directly (split to fp16 hi/lo in VALU).
// z = 5*tanh((c1+b1)/5) + (c2+b2) written fused.
// A LDS: 128 rows x 32 floats, 16B chunks slot-swizzled: slot = chunk ^ (row&7)
//   (staging: LDS position p -> row=p>>3, slot=p&7, global chunk = slot^(row&7))
// B LDS: fp16, q2 XOR swizzle (unchanged from R3, conflict-free verified).
#define TM 128
#define TN 128
#define BK 32
__global__ __launch_bounds__(256, 2) void gemm_paired_kernel(
    const float* __restrict__ u,
    const unsigned short* __restrict__ wh, const unsigned short* __restrict__ wl,
    const float* __restrict__ bias,
    float* __restrict__ z_out) {   // M_ x MEM
    __shared__ __attribute__((aligned(16))) float Af[TM * BK];            // 16 KB
    __shared__ __attribute__((aligned(16))) unsigned short Bh0[TN * BK];  // 8 KB
    __shared__ __attribute__((aligned(16))) unsigned short Bl0[TN * BK];
    __shared__ __attribute__((aligned(16))) unsigned short Bh1[TN * BK];
    __shared__ __attribute__((aligned(16))) unsigned short Bl1[TN * BK];

    const int tid = threadIdx.x;
    // supertile: group of 64 blocks = 8 M-tiles (fast) x 8 N-pairs
    const int id  = blockIdx.x;                  // 0..4095
    const int mt  = (id >> 6) * 8 + (id & 7);    // 0..511
    const int nt  = (id >> 3) & 7;               // 0..7
    const int tileM = mt * TM;
    const int tileN = nt * TN;

    const int lane = tid & 63, w = tid >> 6;
    const int wm = w & 1, wn = w >> 1;
    const int lrow = lane & 15, quad = lane >> 4;
    const int q2 = quad ^ ((lrow >> 1) & 3);     // B bank-conflict XOR swizzle

    f32x4 acc0[4][4] = {};
    f32x4 acc1[4][4] = {};

    // A staging: 4 calls of 256 lanes x 16B cover 128x32 floats.
    size_t aoff[4];
#pragma unroll
    for (int c = 0; c < 4; ++c) {
        const int p = c * 256 + tid;          // LDS chunk index
        const int row = p >> 3;
        const int chunk = (p & 7) ^ (row & 7);
        aoff[c] = (size_t)(tileM + row) * K_ + chunk * 4;
    }
    // B staging (fp16, 2 chunks per tile per thread), q2-swizzled source.
    const int i0 = tid, i1 = tid + 256;
    const int r0 = i0 >> 2, gs0 = (i0 & 3) ^ ((r0 >> 1) & 3);
    const int r1 = i1 >> 2, gs1 = (i1 & 3) ^ ((r1 >> 1) & 3);
    const size_t sB0a = (size_t)(tileN + r0) * K_ + gs0 * 8;
    const size_t sB0b = (size_t)(tileN + r1) * K_ + gs1 * 8;
    const size_t sB1a = (size_t)(tileN + 1024 + r0) * K_ + gs0 * 8;
    const size_t sB1b = (size_t)(tileN + 1024 + r1) * K_ + gs1 * 8;

    for (int kt = 0; kt < K_ / BK; ++kt) {
        const size_t ko = (size_t)kt * BK;     // k-elements (floats for u, shorts for w)
        __syncthreads();
#pragma unroll
        for (int c = 0; c < 4; ++c)
            gl_lds16(u + aoff[c] + ko, &Af[c * 1024 + tid * 4]);
        gl_lds16(wh + sB0a + ko, &Bh0[i0 * 8]);
        gl_lds16(wh + sB0b + ko, &Bh0[i1 * 8]);
        gl_lds16(wl + sB0a + ko, &Bl0[i0 * 8]);
        gl_lds16(wl + sB0b + ko, &Bl0[i1 * 8]);
        gl_lds16(wh + sB1a + ko, &Bh1[i0 * 8]);
        gl_lds16(wh + sB1b + ko, &Bh1[i1 * 8]);
        gl_lds16(wl + sB1a + ko, &Bl1[i0 * 8]);
        gl_lds16(wl + sB1b + ko, &Bl1[i1 * 8]);
        __syncthreads();

        // A fragments: read fp32, split to fp16 hi/lo in VALU.
        half8 ahf[4], alf[4];
#pragma unroll
        for (int i = 0; i < 4; ++i) {
            const int r = wm * 64 + i * 16 + lrow;
            const int sw = r & 7;
            const f32x4 t0 = *(const f32x4*)&Af[(r * 8 + ((quad * 2)     ^ sw)) * 4];
            const f32x4 t1 = *(const f32x4*)&Af[(r * 8 + ((quad * 2 + 1) ^ sw)) * 4];
            half8 h, l;
#pragma unroll
            for (int e = 0; e < 4; ++e) {
                float xs = t0[e] * SCALE_U;
                _Float16 hh = (_Float16)xs;
                h[e] = hh;
                l[e] = (_Float16)(xs - (float)hh);
                xs = t1[e] * SCALE_U;
                hh = (_Float16)xs;
                h[e + 4] = hh;
                l[e + 4] = (_Float16)(xs - (float)hh);
            }
            ahf[i] = h; alf[i] = l;
        }
#pragma unroll
        for (int j = 0; j < 4; ++j) {
            const int bo = ((wn * 64 + j * 16 + lrow) * 4 + q2) * 8;
            const half8 b0h = *(const half8*)&Bh0[bo];
            const half8 b0l = *(const half8*)&Bl0[bo];
            const half8 b1h = *(const half8*)&Bh1[bo];
            const half8 b1l = *(const half8*)&Bl1[bo];
#pragma unroll
            for (int i = 0; i < 4; ++i) {
                f32x4 c0 = acc0[i][j];
                c0 = __builtin_amdgcn_mfma_f32_16x16x32_f16(ahf[i], b0h, c0, 0, 0, 0);
                c0 = __builtin_amdgcn_mfma_f32_16x16x32_f16(ahf[i], b0l, c0, 0, 0, 0);
                c0 = __builtin_amdgcn_mfma_f32_16x16x32_f16(alf[i], b0h, c0, 0, 0, 0);
                acc0[i][j] = c0;
                f32x4 c1 = acc1[i][j];
                c1 = __builtin_amdgcn_mfma_f32_16x16x32_f16(ahf[i], b1h, c1, 0, 0, 0);
                c1 = __builtin_amdgcn_mfma_f32_16x16x32_f16(ahf[i], b1l, c1, 0, 0, 0);
                c1 = __builtin_amdgcn_mfma_f32_16x16x32_f16(alf[i], b1h, c1, 0, 0, 0);
                acc1[i][j] = c1;
            }
        }
    }

    // Epilogue: fused z = 5*tanh((c1+b1)/5) + (c2+b2).
#pragma unroll
    for (int j = 0; j < 4; ++j) {
        const int c = tileN + wn * 64 + j * 16 + lrow;
        const float b1v = bias[c];
        const float b2v = bias[c + 1024];
#pragma unroll
        for (int i = 0; i < 4; ++i) {
            const int rowb = tileM + wm * 64 + i * 16 + quad * 4;
#pragma unroll
            for (int r = 0; r < 4; ++r) {
                float v1 = acc0[i][j][r] * INV_SCALE + b1v;
                v1 = fast_tanh(v1 * 0.2f) * 5.0f;
                const float v2 = acc1[i][j][r] * INV_SCALE + b2v;
                z_out[(size_t)(rowb + r) * MEM + c] = v1 + v2;
            }
        }
    }
}

// One thread per (b, m) chain; 16-deep register prefetch (4 KB/wave in flight).
__global__ __launch_bounds__(256) void scan_kernel(
    const float* __restrict__ z,      // M_ x MEM fused io+sb
    float* __restrict__ h_t,          // out: hf sequence
    const float* __restrict__ h0,
    float* __restrict__ hf_last) {
    const int idx = blockIdx.x * 256 + threadIdx.x;   // 0 .. 131071
    const int b = idx >> 10, m = idx & (MEM - 1);
    float hf = h0[idx];
    float hs = h0[B_ * MEM + idx];
    const size_t base = (size_t)b * L_ * MEM + m;

    float zv[16], zn[16];
#pragma unroll
    for (int j = 0; j < 16; ++j) zv[j] = z[base + (size_t)j * MEM];

    for (int l0 = 0; l0 < L_; l0 += 16) {
        const bool more = (l0 + 16) < L_;
        if (more) {
#pragma unroll
            for (int j = 0; j < 16; ++j)
                zn[j] = z[base + (size_t)(l0 + 16 + j) * MEM];
        }
#pragma unroll
        for (int j = 0; j < 16; ++j) {
            const float hsb = hs + 0.4f;
            const float x = zv[j] + 4.0f * hf - 7.0f * hsb * hsb;
            const float hfn = fast_tanh(x);
            const float eps = 0.9f + 0.9f * fast_sigmoid(10.0f * (hf - 0.5f));
            hs = hs + eps * (hf - hs);
            h_t[base + (size_t)(l0 + j) * MEM] = hfn;
            hf = hfn;
        }
        if (more) {
#pragma unroll
            for (int j = 0; j < 16; ++j) zv[j] = zn[j];
        }
    }
    hf_last[idx] = hf;
}

extern "C" void kernel_launch(void* const* d_in, const int* in_sizes, int n_in,
                              void* d_out, int out_size, void* d_ws, size_t ws_size,
                              hipStream_t stream) {
    const float* u    = (const float*)d_in[0];   // (128,512,512)
    const float* h0   = (const float*)d_in[1];   // (2,128,1024)
    const float* W_im = (const float*)d_in[2];   // (2048,512)
    const float* b_im = (const float*)d_in[3];   // (2048,)

    float* out = (float*)d_out;
    float* h_t = out;
    float* hf_last = out + (size_t)M_ * MEM;

    // ws layout (~273 MB):
    //   z   : M_*MEM fp32      = 268,435,456 B
    //   wh  : N_*K_  fp16      =   2,097,152 B
    //   wl  : N_*K_  fp16      =   2,097,152 B
    char* ws = (char*)d_ws;
    float* z           = (float*)ws;
    unsigned short* wh = (unsigned short*)(ws + 268435456ull);
    unsigned short* wl = (unsigned short*)(ws + 270532608ull);

    // 1) split W fp32 -> fp16 hi/lo (scaled)
    {
        const int n4_w = (N_ * K_) / 4;
        split_fp32_fp16x2<<<(n4_w + 255) / 256, 256, 0, stream>>>(W_im, wh, wl, n4_w, SCALE_W);
    }
    // 2) paired GEMM (fp32-A on-the-fly split) -> fused z
    {
        gemm_paired_kernel<<<4096, 256, 0, stream>>>(u, wh, wl, b_im, z);
    }
    // 3) recurrence scan + hf_last
    {
        scan_kernel<<<(B_ * MEM) / 256, 256, 0, stream>>>(z, h_t, h0, hf_last);
    }
}